// Round 2
// baseline (847.207 us; speedup 1.0000x reference)
//
#include <hip/hip_runtime.h>

// GCN 3-layer forward, fp32. N=100000 nodes, E=1.6M edges, HID=128, N_CLS=40.
// Workspace layout: Y[N*128] f32 | H[N*128] f32 | csr[E] i32 | rowptr[N+1] i32 |
// deg[N] i32 | cursor[N] i32 | norm[N] f32 | maskflag i32   (~110.5 MB)

__global__ void k_deg(const int* __restrict__ dst, int* __restrict__ deg, int E) {
    int e = blockIdx.x * 256 + threadIdx.x;
    if (e < E) atomicAdd(&deg[dst[e]], 1);
}

__global__ __launch_bounds__(1024) void k_scan(const int* __restrict__ deg,
                                               int* __restrict__ rowptr,
                                               float* __restrict__ normv, int n) {
    __shared__ int part[1024];
    int t = threadIdx.x;
    int chunk = (n + 1023) >> 10;
    int lo = t * chunk, hi = min(lo + chunk, n);
    int s = 0;
    for (int i = lo; i < hi; ++i) s += deg[i];
    part[t] = s;
    __syncthreads();
    for (int off = 1; off < 1024; off <<= 1) {
        int v = (t >= off) ? part[t - off] : 0;
        __syncthreads();
        part[t] += v;
        __syncthreads();
    }
    int run = (t == 0) ? 0 : part[t - 1];
    for (int i = lo; i < hi; ++i) {
        rowptr[i] = run;
        int d = deg[i];
        normv[i] = 1.0f / fmaxf((float)d, 1.0f);
        run += d;
    }
    if (t == 1023) rowptr[n] = run;  // == E
}

__global__ void k_scatter(const int* __restrict__ src, const int* __restrict__ dst,
                          const int* __restrict__ rowptr, int* __restrict__ cursor,
                          int* __restrict__ csr, int E) {
    int e = blockIdx.x * 256 + threadIdx.x;
    if (e < E) {
        int d = dst[e];
        int p = atomicAdd(&cursor[d], 1);
        csr[rowptr[d] + p] = src[e];
    }
}

// Detect mask dtype: if any of the first 1024 words is not 0/1, the mask is a
// byte (bool) array (random 0/1 bytes packed 4-per-word); else it's int32.
__global__ void k_maskdet(const unsigned* __restrict__ m, int* __restrict__ flag) {
    unsigned v = m[blockIdx.x * 256 + threadIdx.x];
    if (v > 1u) atomicOr(flag, 1);
}

// Y[r][c] = sum_k X[r][k] * W[k][c].  K=128 processed in two 64-wide chunks so
// LDS = 32K (Xs) + 32K/16K (Ws) stays <= 64 KB per workgroup.
// 256 threads; per-thread 8 rows x TN cols. Xs XOR-swizzled on k so the 8
// per-row ds_read_b128 fragment loads are 4 distinct 16B addrs x 16-lane
// broadcast (conflict-free). Ws reads: 16 addrs x 16B = 2-way (free).
template<int BN>
__global__ __launch_bounds__(256) void k_gemm(const float* __restrict__ X,
                                              const float* __restrict__ Wg,
                                              float* __restrict__ Y,
                                              int nrows, int wcols) {
    constexpr int TN = BN / 16;  // 8 or 4
    __shared__ float Xs[128][64];
    __shared__ float Ws[64][BN];
    int t = threadIdx.x;
    int bm = blockIdx.x * 128;
    int tx = t & 15, ty = t >> 4;
    int sw = (ty & 3) << 2;

    float acc[8][TN];
#pragma unroll
    for (int i = 0; i < 8; ++i)
#pragma unroll
        for (int j = 0; j < TN; ++j) acc[i][j] = 0.0f;

    for (int kc = 0; kc < 128; kc += 64) {
        // stage X chunk: 128 rows x 16 float4
        for (int idx = t; idx < 128 * 16; idx += 256) {
            int row = idx >> 4, k4 = idx & 15;
            int grow = bm + row;
            if (grow >= nrows) grow = nrows - 1;  // clamp: dup load, unused result
            float4 v = *(const float4*)(X + (size_t)grow * 128 + kc + k4 * 4);
            int kk2 = (k4 * 4) ^ (((row >> 3) & 3) << 2);
            *(float4*)&Xs[row][kk2] = v;
        }
        // stage W chunk
        if (BN == 128) {
            for (int idx = t; idx < 64 * 32; idx += 256) {
                int k = idx >> 5, c4 = idx & 31;
                *(float4*)&Ws[k][c4 * 4] =
                    *(const float4*)(Wg + (size_t)(kc + k) * 128 + c4 * 4);
            }
        } else {
            for (int idx = t; idx < 64 * BN; idx += 256) {
                int k = idx / BN, c = idx % BN;
                Ws[k][c] = (c < wcols) ? Wg[(size_t)(kc + k) * wcols + c] : 0.0f;
            }
        }
        __syncthreads();

        for (int k = 0; k < 64; k += 4) {
            float4 a4[8];
#pragma unroll
            for (int i = 0; i < 8; ++i)
                a4[i] = *(const float4*)&Xs[ty * 8 + i][k ^ sw];
#pragma unroll
            for (int kk = 0; kk < 4; ++kk) {
                float b[TN];
                *(float4*)&b[0] = *(const float4*)&Ws[k + kk][tx * 4];
                if (BN == 128)
                    *(float4*)&b[4] = *(const float4*)&Ws[k + kk][64 + tx * 4];
#pragma unroll
                for (int i = 0; i < 8; ++i) {
                    float a = ((const float*)&a4[i])[kk];
#pragma unroll
                    for (int j = 0; j < TN; ++j) acc[i][j] += a * b[j];
                }
            }
        }
        __syncthreads();
    }

#pragma unroll
    for (int i = 0; i < 8; ++i) {
        int r = bm + ty * 8 + i;
        if (r < nrows) {
            *(float4*)(Y + (size_t)r * BN + tx * 4) = *(const float4*)&acc[i][0];
            if (BN == 128)
                *(float4*)(Y + (size_t)r * BN + 64 + tx * 4) = *(const float4*)&acc[i][4];
        }
    }
}

// One block per dst node; thread c accumulates feature c over in-edges
// (coalesced 4B*width row loads), then norm+bias (+relu+dropout mask).
// mflag: 0 -> mask stored as int32, 1 -> mask stored as bytes.
template<bool ACT>
__global__ void k_spmm(const float* __restrict__ Y, int ldy,
                       const int* __restrict__ rowptr, const int* __restrict__ csr,
                       const float* __restrict__ normv, const float* __restrict__ bias,
                       const void* __restrict__ mask, const int* __restrict__ mflag,
                       float* __restrict__ H, int ldh, int width) {
    int i = blockIdx.x;
    int c = threadIdx.x;
    if (c >= width) return;
    int lo = rowptr[i], hi = rowptr[i + 1];
    float acc = 0.0f;
    int e = lo;
    for (; e + 3 < hi; e += 4) {
        int s0 = csr[e], s1 = csr[e + 1], s2 = csr[e + 2], s3 = csr[e + 3];
        acc += Y[(size_t)s0 * ldy + c];
        acc += Y[(size_t)s1 * ldy + c];
        acc += Y[(size_t)s2 * ldy + c];
        acc += Y[(size_t)s3 * ldy + c];
    }
    for (; e < hi; ++e) acc += Y[(size_t)csr[e] * ldy + c];
    float v = acc * normv[i] + bias[c];
    if (ACT) {
        v = v > 0.0f ? v : 0.0f;
        size_t j = (size_t)i * 128 + c;
        bool keep;
        if (*mflag != 0) keep = ((const unsigned char*)mask)[j] != 0;
        else             keep = ((const int*)mask)[j] != 0;
        v = keep ? v * 2.0f : 0.0f;  // KEEP=0.5 -> /0.5
    }
    H[(size_t)i * ldh + c] = v;
}

extern "C" void kernel_launch(void* const* d_in, const int* in_sizes, int n_in,
                              void* d_out, int out_size, void* d_ws, size_t ws_size,
                              hipStream_t stream) {
    const float* feat = (const float*)d_in[0];
    const int* src = (const int*)d_in[1];
    const int* dst = (const int*)d_in[2];
    const void* mask1 = d_in[3];
    const void* mask2 = d_in[4];
    const float* w0 = (const float*)d_in[5];
    const float* b0 = (const float*)d_in[6];
    const float* w1 = (const float*)d_in[7];
    const float* b1 = (const float*)d_in[8];
    const float* w2 = (const float*)d_in[9];
    const float* b2 = (const float*)d_in[10];
    int N = in_sizes[0] / 128;
    int E = in_sizes[1];
    int ncls = in_sizes[10];  // 40

    float* out = (float*)d_out;
    float* Y = (float*)d_ws;
    float* H = Y + (size_t)N * 128;
    int* csr = (int*)(H + (size_t)N * 128);
    int* rowptr = csr + E;
    int* deg = rowptr + (N + 1);
    int* cursor = deg + N;
    float* normv = (float*)(cursor + N);
    int* mflag = (int*)(normv + N);

    hipMemsetAsync(deg, 0, (size_t)N * 4, stream);
    hipMemsetAsync(cursor, 0, (size_t)N * 4, stream);
    hipMemsetAsync(mflag, 0, 4, stream);
    k_maskdet<<<4, 256, 0, stream>>>((const unsigned*)mask1, mflag);
    int eb = (E + 255) / 256;
    k_deg<<<eb, 256, 0, stream>>>(dst, deg, E);
    k_scan<<<1, 1024, 0, stream>>>(deg, rowptr, normv, N);
    k_scatter<<<eb, 256, 0, stream>>>(src, dst, rowptr, cursor, csr, E);

    int gb = (N + 127) / 128;
    k_gemm<128><<<gb, 256, 0, stream>>>(feat, w0, Y, N, 128);
    k_spmm<true><<<N, 128, 0, stream>>>(Y, 128, rowptr, csr, normv, b0, mask1, mflag, H, 128, 128);
    k_gemm<128><<<gb, 256, 0, stream>>>(H, w1, Y, N, 128);
    k_spmm<true><<<N, 128, 0, stream>>>(Y, 128, rowptr, csr, normv, b1, mask2, mflag, H, 128, 128);
    k_gemm<64><<<gb, 256, 0, stream>>>(H, w2, Y, N, ncls);
    k_spmm<false><<<N, 64, 0, stream>>>(Y, 64, rowptr, csr, normv, b2, nullptr, mflag, out, ncls, ncls);
}

// Round 3
// 630.938 us; speedup vs baseline: 1.3428x; 1.3428x over previous
//
#include <hip/hip_runtime.h>

// GCN 3-layer forward, fp32. N=100000 nodes, E=1.6M edges, HID=128, N_CLS=40.
// Workspace layout: Y[N*128] f32 | H[N*128] f32 | csr[E] i32 | rowptr[N+1] i32 |
// deg[N] i32 | cursor[N] i32 | norm[N] f32 | maskflag i32 | part[nb] i32

__global__ void k_deg(const int* __restrict__ dst, int* __restrict__ deg, int E) {
    int e = blockIdx.x * 256 + threadIdx.x;
    if (e < E) atomicAdd(&deg[dst[e]], 1);
}

// --- parallel prefix sum over deg (3 kernels, EPB=1024 elements/block) ---
__global__ __launch_bounds__(256) void k_part(const int* __restrict__ deg,
                                              int* __restrict__ part, int n) {
    __shared__ int red[256];
    int t = threadIdx.x;
    int base = blockIdx.x * 1024 + t * 4;
    int s = 0;
#pragma unroll
    for (int j = 0; j < 4; ++j) {
        int i = base + j;
        if (i < n) s += deg[i];
    }
    red[t] = s;
    __syncthreads();
    for (int off = 128; off > 0; off >>= 1) {
        if (t < off) red[t] += red[t + off];
        __syncthreads();
    }
    if (t == 0) part[blockIdx.x] = red[0];
}

// single small block: exclusive-scan the nb (<=1024) partials in LDS; total -> rowptr[n]
__global__ __launch_bounds__(256) void k_scanpart(int* __restrict__ part,
                                                  int* __restrict__ rowptr,
                                                  int nb, int n) {
    __shared__ int buf[1024];
    int t = threadIdx.x;
    for (int i = t; i < nb; i += 256) buf[i] = part[i];
    __syncthreads();
    if (t == 0) {
        int run = 0;
        for (int i = 0; i < nb; ++i) {
            int v = buf[i];
            buf[i] = run;
            run += v;
        }
        rowptr[n] = run;  // == E
    }
    __syncthreads();
    for (int i = t; i < nb; i += 256) part[i] = buf[i];
}

__global__ __launch_bounds__(256) void k_rowptr(const int* __restrict__ deg,
                                                const int* __restrict__ part,
                                                int* __restrict__ rowptr,
                                                float* __restrict__ normv, int n) {
    __shared__ int ts[256];
    int t = threadIdx.x;
    int base = blockIdx.x * 1024 + t * 4;
    int d[4];
    int s = 0;
#pragma unroll
    for (int j = 0; j < 4; ++j) {
        int i = base + j;
        d[j] = (i < n) ? deg[i] : 0;
        s += d[j];
    }
    ts[t] = s;
    __syncthreads();
    for (int off = 1; off < 256; off <<= 1) {  // Hillis-Steele inclusive
        int v = (t >= off) ? ts[t - off] : 0;
        __syncthreads();
        ts[t] += v;
        __syncthreads();
    }
    int run = part[blockIdx.x] + ((t == 0) ? 0 : ts[t - 1]);
#pragma unroll
    for (int j = 0; j < 4; ++j) {
        int i = base + j;
        if (i < n) {
            rowptr[i] = run;
            normv[i] = 1.0f / fmaxf((float)d[j], 1.0f);
            run += d[j];
        }
    }
}

__global__ void k_scatter(const int* __restrict__ src, const int* __restrict__ dst,
                          const int* __restrict__ rowptr, int* __restrict__ cursor,
                          int* __restrict__ csr, int E) {
    int e = blockIdx.x * 256 + threadIdx.x;
    if (e < E) {
        int d = dst[e];
        int p = atomicAdd(&cursor[d], 1);
        csr[rowptr[d] + p] = src[e];
    }
}

// Detect mask dtype: any word >1 in first 1024 words -> packed bytes (bool).
__global__ void k_maskdet(const unsigned* __restrict__ m, int* __restrict__ flag) {
    unsigned v = m[blockIdx.x * 256 + threadIdx.x];
    if (v > 1u) atomicOr(flag, 1);
}

// Y[r][c] = sum_k X[r][k] * W[k][c].  K=128 in two 64-wide chunks, LDS <= 64KB.
// 256 threads; per-thread 8 rows x TN cols. Xs XOR-swizzled on k (conflict-free
// ds_read_b128: 4 addrs x 16-lane broadcast). Ws reads 16 addrs x 16B = 2-way.
template<int BN>
__global__ __launch_bounds__(256) void k_gemm(const float* __restrict__ X,
                                              const float* __restrict__ Wg,
                                              float* __restrict__ Y,
                                              int nrows, int wcols) {
    constexpr int TN = BN / 16;  // 8 or 4
    __shared__ float Xs[128][64];
    __shared__ float Ws[64][BN];
    int t = threadIdx.x;
    int bm = blockIdx.x * 128;
    int tx = t & 15, ty = t >> 4;
    int sw = (ty & 3) << 2;

    float acc[8][TN];
#pragma unroll
    for (int i = 0; i < 8; ++i)
#pragma unroll
        for (int j = 0; j < TN; ++j) acc[i][j] = 0.0f;

    for (int kc = 0; kc < 128; kc += 64) {
        for (int idx = t; idx < 128 * 16; idx += 256) {
            int row = idx >> 4, k4 = idx & 15;
            int grow = bm + row;
            if (grow >= nrows) grow = nrows - 1;
            float4 v = *(const float4*)(X + (size_t)grow * 128 + kc + k4 * 4);
            int kk2 = (k4 * 4) ^ (((row >> 3) & 3) << 2);
            *(float4*)&Xs[row][kk2] = v;
        }
        if (BN == 128) {
            for (int idx = t; idx < 64 * 32; idx += 256) {
                int k = idx >> 5, c4 = idx & 31;
                *(float4*)&Ws[k][c4 * 4] =
                    *(const float4*)(Wg + (size_t)(kc + k) * 128 + c4 * 4);
            }
        } else {
            for (int idx = t; idx < 64 * BN; idx += 256) {
                int k = idx / BN, c = idx % BN;
                Ws[k][c] = (c < wcols) ? Wg[(size_t)(kc + k) * wcols + c] : 0.0f;
            }
        }
        __syncthreads();

        for (int k = 0; k < 64; k += 4) {
            float4 a4[8];
#pragma unroll
            for (int i = 0; i < 8; ++i)
                a4[i] = *(const float4*)&Xs[ty * 8 + i][k ^ sw];
#pragma unroll
            for (int kk = 0; kk < 4; ++kk) {
                float b[TN];
                *(float4*)&b[0] = *(const float4*)&Ws[k + kk][tx * 4];
                if (BN == 128)
                    *(float4*)&b[4] = *(const float4*)&Ws[k + kk][64 + tx * 4];
#pragma unroll
                for (int i = 0; i < 8; ++i) {
                    float a = ((const float*)&a4[i])[kk];
#pragma unroll
                    for (int j = 0; j < TN; ++j) acc[i][j] += a * b[j];
                }
            }
        }
        __syncthreads();
    }

#pragma unroll
    for (int i = 0; i < 8; ++i) {
        int r = bm + ty * 8 + i;
        if (r < nrows) {
            *(float4*)(Y + (size_t)r * BN + tx * 4) = *(const float4*)&acc[i][0];
            if (BN == 128)
                *(float4*)(Y + (size_t)r * BN + 64 + tx * 4) = *(const float4*)&acc[i][4];
        }
    }
}

// One block per dst node; thread c accumulates feature c over in-edges,
// then norm+bias (+relu+dropout mask). mflag: 0 -> int32 mask, 1 -> byte mask.
template<bool ACT>
__global__ void k_spmm(const float* __restrict__ Y, int ldy,
                       const int* __restrict__ rowptr, const int* __restrict__ csr,
                       const float* __restrict__ normv, const float* __restrict__ bias,
                       const void* __restrict__ mask, const int* __restrict__ mflag,
                       float* __restrict__ H, int ldh, int width) {
    int i = blockIdx.x;
    int c = threadIdx.x;
    if (c >= width) return;
    int lo = rowptr[i], hi = rowptr[i + 1];
    float acc = 0.0f;
    int e = lo;
    for (; e + 3 < hi; e += 4) {
        int s0 = csr[e], s1 = csr[e + 1], s2 = csr[e + 2], s3 = csr[e + 3];
        acc += Y[(size_t)s0 * ldy + c];
        acc += Y[(size_t)s1 * ldy + c];
        acc += Y[(size_t)s2 * ldy + c];
        acc += Y[(size_t)s3 * ldy + c];
    }
    for (; e < hi; ++e) acc += Y[(size_t)csr[e] * ldy + c];
    float v = acc * normv[i] + bias[c];
    if (ACT) {
        v = v > 0.0f ? v : 0.0f;
        size_t j = (size_t)i * 128 + c;
        bool keep;
        if (*mflag != 0) keep = ((const unsigned char*)mask)[j] != 0;
        else             keep = ((const int*)mask)[j] != 0;
        v = keep ? v * 2.0f : 0.0f;  // KEEP=0.5 -> /0.5
    }
    H[(size_t)i * ldh + c] = v;
}

extern "C" void kernel_launch(void* const* d_in, const int* in_sizes, int n_in,
                              void* d_out, int out_size, void* d_ws, size_t ws_size,
                              hipStream_t stream) {
    const float* feat = (const float*)d_in[0];
    const int* src = (const int*)d_in[1];
    const int* dst = (const int*)d_in[2];
    const void* mask1 = d_in[3];
    const void* mask2 = d_in[4];
    const float* w0 = (const float*)d_in[5];
    const float* b0 = (const float*)d_in[6];
    const float* w1 = (const float*)d_in[7];
    const float* b1 = (const float*)d_in[8];
    const float* w2 = (const float*)d_in[9];
    const float* b2 = (const float*)d_in[10];
    int N = in_sizes[0] / 128;
    int E = in_sizes[1];
    int ncls = in_sizes[10];  // 40

    float* out = (float*)d_out;
    float* Y = (float*)d_ws;
    float* H = Y + (size_t)N * 128;
    int* csr = (int*)(H + (size_t)N * 128);
    int* rowptr = csr + E;
    int* deg = rowptr + (N + 1);
    int* cursor = deg + N;
    float* normv = (float*)(cursor + N);
    int* mflag = (int*)(normv + N);
    int* part = mflag + 1;

    int nb = (N + 1023) / 1024;  // 98

    hipMemsetAsync(deg, 0, (size_t)N * 4, stream);
    hipMemsetAsync(cursor, 0, (size_t)N * 4, stream);
    hipMemsetAsync(mflag, 0, 4, stream);
    k_maskdet<<<4, 256, 0, stream>>>((const unsigned*)mask1, mflag);
    int eb = (E + 255) / 256;
    k_deg<<<eb, 256, 0, stream>>>(dst, deg, E);
    k_part<<<nb, 256, 0, stream>>>(deg, part, N);
    k_scanpart<<<1, 256, 0, stream>>>(part, rowptr, nb, N);
    k_rowptr<<<nb, 256, 0, stream>>>(deg, part, rowptr, normv, N);
    k_scatter<<<eb, 256, 0, stream>>>(src, dst, rowptr, cursor, csr, E);

    int gb = (N + 127) / 128;
    k_gemm<128><<<gb, 256, 0, stream>>>(feat, w0, Y, N, 128);
    k_spmm<true><<<N, 128, 0, stream>>>(Y, 128, rowptr, csr, normv, b0, mask1, mflag, H, 128, 128);
    k_gemm<128><<<gb, 256, 0, stream>>>(H, w1, Y, N, 128);
    k_spmm<true><<<N, 128, 0, stream>>>(Y, 128, rowptr, csr, normv, b1, mask2, mflag, H, 128, 128);
    k_gemm<64><<<gb, 256, 0, stream>>>(H, w2, Y, N, ncls);
    k_spmm<false><<<N, 64, 0, stream>>>(Y, 64, rowptr, csr, normv, b2, nullptr, mflag, out, ncls, ncls);
}